// Round 2
// baseline (1814.976 us; speedup 1.0000x reference)
//
#include <hip/hip_runtime.h>
#include <hip/hip_bf16.h>
#include <cmath>
#include <cstdint>

// SparseMoE: B=2,S=2048 -> 4096 tokens, E=1024, N=8 experts, H=4096, top_k=2.
// Harness I/O is fp32 (threshold = 2% relative => _any_bf16 false).
// Internally: bf16 MFMA grouped GEMM (only top-k experts matter: softmax of
// -inf-masked logits zeroes the rest exactly).

typedef unsigned short u16;
typedef __attribute__((ext_vector_type(8))) short bf16x8;   // MFMA A/B frag (4 VGPR)
typedef __attribute__((ext_vector_type(4))) float f32x4;    // MFMA C/D frag
typedef __attribute__((ext_vector_type(8))) unsigned short us8;
typedef __attribute__((ext_vector_type(4))) unsigned short us4;

#define TOKENS  4096
#define EDIM    1024
#define NEXP    8
#define HDIM    4096
#define HC      1024      // H chunk
#define NCHUNK  4
#define MAXROWS 8192      // top_k(=2) * TOKENS

__device__ __forceinline__ u16 f2bf(float f) {
  __hip_bfloat16 h = __float2bfloat16(f);   // RNE
  return *reinterpret_cast<u16*>(&h);
}
// async global->LDS, 16B per lane; lds base wave-uniform (HW adds lane*16)
__device__ __forceinline__ void async16(void* lds, const void* g) {
  __builtin_amdgcn_global_load_lds((const __attribute__((address_space(1))) void*)g,
                                   (__attribute__((address_space(3))) void*)lds,
                                   16, 0, 0);
}

// ---------------- cast x (fp32) -> xb (bf16) ----------------
__global__ void cast_x_k(const float* __restrict__ x, u16* __restrict__ xb) {
  const int i = blockIdx.x * 256 + threadIdx.x;     // 1 float4 per thread
  float4 v = ((const float4*)x)[i];
  us4 o; o[0] = f2bf(v.x); o[1] = f2bf(v.y); o[2] = f2bf(v.z); o[3] = f2bf(v.w);
  ((us4*)xb)[i] = o;
}

// ---------------- router: logits, top-k, softmax, expert lists ----------------
__global__ void router_k(const float* __restrict__ x, const float* __restrict__ Wr,
                         const float* __restrict__ br, const int* __restrict__ topk_p,
                         int* __restrict__ counts, int* __restrict__ sel_e,
                         int* __restrict__ sel_pos, float* __restrict__ sel_w) {
  const int t = blockIdx.x;
  const int lane = threadIdx.x;             // 64 threads = 1 wave
  float acc[NEXP];
#pragma unroll
  for (int n = 0; n < NEXP; ++n) acc[n] = 0.f;
  const float* xr = x + (size_t)t * EDIM;
  for (int ei = lane; ei < EDIM; ei += 64) {
    float xv = xr[ei];
    float4 w0 = *(const float4*)(Wr + ei * NEXP);
    float4 w1 = *(const float4*)(Wr + ei * NEXP + 4);
    acc[0] += xv * w0.x; acc[1] += xv * w0.y; acc[2] += xv * w0.z; acc[3] += xv * w0.w;
    acc[4] += xv * w1.x; acc[5] += xv * w1.y; acc[6] += xv * w1.z; acc[7] += xv * w1.w;
  }
#pragma unroll
  for (int s = 32; s > 0; s >>= 1) {
#pragma unroll
    for (int n = 0; n < NEXP; ++n) acc[n] += __shfl_down(acc[n], s);
  }
  if (lane == 0) {
    float logit[NEXP];
#pragma unroll
    for (int n = 0; n < NEXP; ++n) logit[n] = acc[n] + br[n];
    int k = topk_p[0]; if (k < 1) k = 1; if (k > NEXP) k = NEXP;
    bool used[NEXP];
#pragma unroll
    for (int n = 0; n < NEXP; ++n) used[n] = false;
    int se[NEXP]; float sw[NEXP];
    for (int j = 0; j < k; ++j) {           // strict > : lowest index wins ties (lax.top_k)
      int bi = 0; float bv = -INFINITY;
      for (int n = 0; n < NEXP; ++n)
        if (!used[n] && logit[n] > bv) { bv = logit[n]; bi = n; }
      used[bi] = true; se[j] = bi; sw[j] = bv;
    }
    float mx = sw[0], sum = 0.f;
    for (int j = 0; j < k; ++j) { sw[j] = expf(sw[j] - mx); sum += sw[j]; }
    float inv = 1.f / sum;
    for (int j = 0; j < k; ++j) {
      int e = se[j];
      int pos = atomicAdd(&counts[e], 1);
      sel_e[t * 8 + j] = e;
      sel_pos[t * 8 + j] = pos;
      sel_w[t * 8 + j] = sw[j] * inv;
    }
  }
}

// ---------------- prefix sums + row->token gather map ----------------
__global__ void prefix_assign_k(const int* __restrict__ counts, int* __restrict__ offsets,
                                const int* __restrict__ sel_e, const int* __restrict__ sel_pos,
                                const int* __restrict__ topk_p, int* __restrict__ row_token) {
  __shared__ int offs[NEXP];
  if (threadIdx.x == 0) {
    int s = 0;
    for (int e = 0; e < NEXP; ++e) { offsets[e] = s; offs[e] = s; s += counts[e]; }
  }
  __syncthreads();
  int k = topk_p[0]; if (k < 1) k = 1; if (k > 8) k = 8;
  for (int i = threadIdx.x; i < TOKENS * k; i += blockDim.x) {
    int t = i / k, j = i - t * k;
    int e = sel_e[t * 8 + j];
    row_token[offs[e] + sel_pos[t * 8 + j]] = t;
  }
}

// ------ transpose+downcast one 1024x1024 chunk of W1 and W2 per expert ------
// z<8:  W1t[e][h][ei]  = bf16(W1[e][ei][h0+h])   (in rows ei, stride HDIM)
// z>=8: W2t[e][ep][h]  = bf16(W2[e][h0+h][ep])   (in rows h,  stride EDIM)
__global__ void transpose_k(const float* __restrict__ W1, const float* __restrict__ W2,
                            u16* __restrict__ W1t, u16* __restrict__ W2t, int h0) {
  __shared__ __align__(16) u16 T[64][68];   // +4 pad: 8B-aligned rows, mild conflicts
  const int z = blockIdx.z;
  const float* in; u16* out; size_t istride;
  if (z < 8) {
    in = W1 + (size_t)z * EDIM * HDIM + h0;                istride = HDIM;
    out = W1t + (size_t)z * 1024 * 1024;
  } else {
    int e = z - 8;
    in = W2 + (size_t)e * HDIM * EDIM + (size_t)h0 * EDIM; istride = EDIM;
    out = W2t + (size_t)e * 1024 * 1024;
  }
  const int r0 = blockIdx.y * 64, c0 = blockIdx.x * 64;
  const int tid = threadIdx.x;
#pragma unroll
  for (int it = 0; it < 4; ++it) {
    int cell = it * 256 + tid;              // 1024 cells: rl(64) x c4(16)
    int rl = cell >> 4, c4 = (cell & 15) * 4;
    float4 v = *(const float4*)(in + (size_t)(r0 + rl) * istride + c0 + c4);
    us4 o; o[0] = f2bf(v.x); o[1] = f2bf(v.y); o[2] = f2bf(v.z); o[3] = f2bf(v.w);
    *(us4*)&T[rl][c4] = o;
  }
  __syncthreads();
#pragma unroll
  for (int it = 0; it < 2; ++it) {
    int cell = it * 256 + tid;              // 512 cells: cl(64) x r8(8)
    int cl = cell >> 3, r8 = (cell & 7) * 8;
    us8 o;
#pragma unroll
    for (int j = 0; j < 8; ++j) o[j] = T[r8 + j][cl];
    *(us8*)(out + (size_t)(c0 + cl) * 1024 + r0 + r8) = o;
  }
}

// ---------------- grouped 128x128x(K=1024) bf16 MFMA GEMM ----------------
// MODE 0: hid[row][n] = gelu(gather(xb) @ W1t^T + b1)      (A gathered via row_token)
// MODE 1: Y[row][n] (+)= hid @ W2t^T (+ b2 on first chunk) (A = compact hid rows)
// LDS layout [kquad][row][8 bf16]: satisfies global_load_lds lane mapping AND
// gives 2-way-max bank pattern for the ds_read_b128 fragment loads.
template <int MODE>
__global__ __launch_bounds__(256, 2) void gemm_k(
    const u16* __restrict__ A, const u16* __restrict__ Bt, const float* __restrict__ bias,
    const int* __restrict__ counts, const int* __restrict__ offsets,
    const int* __restrict__ row_token,
    u16* __restrict__ hid, float* __restrict__ Y, int h0, int accum) {
  const int e = blockIdx.z;
  const int cnt = counts[e];
  const int m0 = blockIdx.x * 128;
  if (m0 >= cnt) return;                    // dynamic expert size: early-exit
  const int n0 = blockIdx.y * 128;
  const int off_e = offsets[e];

  __shared__ __align__(16) u16 As[4096];    // 4 quads x 128 rows x 8
  __shared__ __align__(16) u16 Bs[4096];

  const int tid = threadIdx.x;
  const int lane = tid & 63;
  const int wave = tid >> 6;

  // staging: thread owns cell (qh = tid>>7, m = tid&127), 16B each, 2 issues
  const int m_me = tid & 127;
  const int qh = tid >> 7;
  int mrow = m0 + m_me; if (mrow > cnt - 1) mrow = cnt - 1;   // clamp tail rows
  size_t arow;
  if (MODE == 0) arow = (size_t)row_token[off_e + mrow] * EDIM;
  else           arow = (size_t)(off_e + mrow) * HC;
  const u16* gA = A + arow;
  const u16* gB = Bt + ((size_t)e * 1024 + n0 + m_me) * 1024;
  u16* lA0 = As + wave * 512;  u16* lA1 = As + 2048 + wave * 512;
  u16* lB0 = Bs + wave * 512;  u16* lB1 = Bs + 2048 + wave * 512;
  const int kq0 = qh * 8, kq1 = 16 + qh * 8;

  const int wm = wave >> 1, wn = wave & 1;
  const int quad = lane >> 4, l15 = lane & 15;
  int aoff[4], boff[4];
#pragma unroll
  for (int mi = 0; mi < 4; ++mi) aoff[mi] = quad * 1024 + (wm * 64 + mi * 16 + l15) * 8;
#pragma unroll
  for (int ni = 0; ni < 4; ++ni) boff[ni] = quad * 1024 + (wn * 64 + ni * 16 + l15) * 8;

  f32x4 acc[4][4];
#pragma unroll
  for (int mi = 0; mi < 4; ++mi)
#pragma unroll
    for (int ni = 0; ni < 4; ++ni) acc[mi][ni] = (f32x4){0.f, 0.f, 0.f, 0.f};

  for (int k0 = 0; k0 < 1024; k0 += 32) {
    __syncthreads();                        // LDS reads of prev iter done
    async16(lA0, gA + k0 + kq0);
    async16(lA1, gA + k0 + kq1);
    async16(lB0, gB + k0 + kq0);
    async16(lB1, gB + k0 + kq1);
    __syncthreads();                        // drains vmcnt -> LDS ready
    bf16x8 a[4], b[4];
#pragma unroll
    for (int mi = 0; mi < 4; ++mi) a[mi] = *(const bf16x8*)(As + aoff[mi]);
#pragma unroll
    for (int ni = 0; ni < 4; ++ni) b[ni] = *(const bf16x8*)(Bs + boff[ni]);
#pragma unroll
    for (int mi = 0; mi < 4; ++mi)
#pragma unroll
      for (int ni = 0; ni < 4; ++ni)
        acc[mi][ni] = __builtin_amdgcn_mfma_f32_16x16x32_bf16(a[mi], b[ni], acc[mi][ni], 0, 0, 0);
  }

  // epilogue: D row = quad*4+r, col = l15 (m89/m91-verified layout)
#pragma unroll
  for (int mi = 0; mi < 4; ++mi) {
    const int mbase = m0 + wm * 64 + mi * 16 + quad * 4;
#pragma unroll
    for (int ni = 0; ni < 4; ++ni) {
      const int nloc = n0 + wn * 64 + ni * 16 + l15;
      float bv;
      if (MODE == 0) bv = bias[e * HDIM + h0 + nloc];
      else           bv = accum ? 0.f : bias[e * EDIM + nloc];
#pragma unroll
      for (int r = 0; r < 4; ++r) {
        const int m = mbase + r;
        if (m < cnt) {
          float v = acc[mi][ni][r] + bv;
          if (MODE == 0) {
            v = 0.5f * v * (1.f + erff(v * 0.70710678118654752f));  // exact gelu
            hid[(size_t)(off_e + m) * HC + nloc] = f2bf(v);
          } else {
            size_t yi = (size_t)(off_e + m) * EDIM + nloc;
            Y[yi] = accum ? (Y[yi] + v) : v;
          }
        }
      }
    }
  }
}

// ---------------- weighted combine over top-k rows ----------------
__global__ void combine_k(const float* __restrict__ Y, const int* __restrict__ sel_e,
                          const int* __restrict__ sel_pos, const float* __restrict__ sel_w,
                          const int* __restrict__ offsets, const int* __restrict__ topk_p,
                          float* __restrict__ out) {
  const int t = blockIdx.x;
  const int tid = threadIdx.x;              // 256 thr x 4 floats
  int k = topk_p[0]; if (k < 1) k = 1; if (k > 8) k = 8;
  float a0 = 0.f, a1 = 0.f, a2 = 0.f, a3 = 0.f;
  for (int j = 0; j < k; ++j) {
    const int e = sel_e[t * 8 + j];
    const float w = sel_w[t * 8 + j];
    const size_t row = (size_t)offsets[e] + sel_pos[t * 8 + j];
    const float4 v = *(const float4*)(Y + row * EDIM + tid * 4);
    a0 += w * v.x; a1 += w * v.y; a2 += w * v.z; a3 += w * v.w;
  }
  float4 o; o.x = a0; o.y = a1; o.z = a2; o.w = a3;
  *(float4*)(out + (size_t)t * EDIM + tid * 4) = o;
}

extern "C" void kernel_launch(void* const* d_in, const int* in_sizes, int n_in,
                              void* d_out, int out_size, void* d_ws, size_t ws_size,
                              hipStream_t stream) {
  const float* x   = (const float*)d_in[0];
  const float* Wr  = (const float*)d_in[1];
  const float* br  = (const float*)d_in[2];
  const float* W1  = (const float*)d_in[3];
  const float* b1  = (const float*)d_in[4];
  const float* W2  = (const float*)d_in[5];
  const float* b2  = (const float*)d_in[6];
  const int* topk  = (const int*)d_in[7];
  float* out = (float*)d_out;

  char* ws = (char*)d_ws;
  size_t o = 0;
  auto alloc = [&](size_t bytes) -> char* {
    char* p = ws + o; o += (bytes + 255) & ~(size_t)255; return p;
  };
  int*   counts    = (int*)alloc(NEXP * 4);
  int*   offsets   = (int*)alloc(NEXP * 4);
  int*   sel_e     = (int*)alloc((size_t)TOKENS * 8 * 4);
  int*   sel_pos   = (int*)alloc((size_t)TOKENS * 8 * 4);
  float* sel_w     = (float*)alloc((size_t)TOKENS * 8 * 4);
  int*   row_token = (int*)alloc((size_t)TOKENS * 8 * 4);
  u16*   xb        = (u16*)alloc((size_t)TOKENS * EDIM * 2);         //  8.4 MB
  u16*   W1t       = (u16*)alloc((size_t)NEXP * 1024 * 1024 * 2);    // 16.8 MB
  u16*   W2t       = (u16*)alloc((size_t)NEXP * 1024 * 1024 * 2);    // 16.8 MB
  u16*   hid       = (u16*)alloc((size_t)MAXROWS * HC * 2);          // 16.8 MB
  float* Y         = (float*)alloc((size_t)MAXROWS * EDIM * 4);      // 33.5 MB
  // total ~= 93 MB of ws

  hipMemsetAsync(counts, 0, NEXP * sizeof(int), stream);
  cast_x_k<<<dim3(TOKENS * EDIM / 1024), dim3(256), 0, stream>>>(x, xb);
  router_k<<<dim3(TOKENS), dim3(64), 0, stream>>>(x, Wr, br, topk,
                                                  counts, sel_e, sel_pos, sel_w);
  prefix_assign_k<<<dim3(1), dim3(256), 0, stream>>>(counts, offsets, sel_e, sel_pos,
                                                     topk, row_token);
  for (int c = 0; c < NCHUNK; ++c) {
    const int h0 = c * HC;
    transpose_k<<<dim3(16, 16, 16), dim3(256), 0, stream>>>(W1, W2, W1t, W2t, h0);
    gemm_k<0><<<dim3(32, 8, 8), dim3(256), 0, stream>>>(xb, W1t, b1, counts, offsets,
                                                        row_token, hid, nullptr, h0, 0);
    gemm_k<1><<<dim3(32, 8, 8), dim3(256), 0, stream>>>(hid, W2t, b2, counts, offsets,
                                                        row_token, nullptr, Y, h0,
                                                        c > 0 ? 1 : 0);
  }
  combine_k<<<dim3(TOKENS), dim3(256), 0, stream>>>(Y, sel_e, sel_pos, sel_w,
                                                    offsets, topk, out);
}

// Round 3
// 1199.926 us; speedup vs baseline: 1.5126x; 1.5126x over previous
//
#include <hip/hip_runtime.h>
#include <hip/hip_bf16.h>
#include <cmath>
#include <cstdint>

// SparseMoE: B=2,S=2048 -> 4096 tokens, E=1024, N=8 experts, H=4096, top_k=2.
// fp32 I/O; internally bf16 MFMA grouped GEMM over the top-k expert rows only.
// R3: coalesced BK=64 staging (1 line = 1 fetch), XOR-swizzled LDS, dense
// pre-gathered A. R2 was transaction-bound (64-line scatter per load inst).

typedef unsigned short u16;
typedef __attribute__((ext_vector_type(8))) short bf16x8;   // MFMA A/B frag (4 VGPR)
typedef __attribute__((ext_vector_type(4))) float f32x4;    // MFMA C/D frag
typedef __attribute__((ext_vector_type(8))) unsigned short us8;
typedef __attribute__((ext_vector_type(4))) unsigned short us4;

#define TOKENS  4096
#define EDIM    1024
#define NEXP    8
#define HDIM    4096
#define HC      1024      // H chunk
#define NCHUNK  4
#define MAXROWS 8192      // top_k(=2) * TOKENS
#define ROWPAD  128       // tail staging may read past cnt; keep in-bounds

__device__ __forceinline__ u16 f2bf(float f) {
  __hip_bfloat16 h = __float2bfloat16(f);   // RNE
  return *reinterpret_cast<u16*>(&h);
}
// async global->LDS, 16B per lane; lds base wave-uniform (HW adds lane*16)
__device__ __forceinline__ void async16(void* lds, const void* g) {
  __builtin_amdgcn_global_load_lds((const __attribute__((address_space(1))) void*)g,
                                   (__attribute__((address_space(3))) void*)lds,
                                   16, 0, 0);
}

// ---------------- router: logits, top-k, softmax, expert lists ----------------
__global__ void router_k(const float* __restrict__ x, const float* __restrict__ Wr,
                         const float* __restrict__ br, const int* __restrict__ topk_p,
                         int* __restrict__ counts, int* __restrict__ sel_e,
                         int* __restrict__ sel_pos, float* __restrict__ sel_w) {
  const int t = blockIdx.x;
  const int lane = threadIdx.x;             // 64 threads = 1 wave
  float acc[NEXP];
#pragma unroll
  for (int n = 0; n < NEXP; ++n) acc[n] = 0.f;
  const float* xr = x + (size_t)t * EDIM;
  for (int ei = lane; ei < EDIM; ei += 64) {
    float xv = xr[ei];
    float4 w0 = *(const float4*)(Wr + ei * NEXP);
    float4 w1 = *(const float4*)(Wr + ei * NEXP + 4);
    acc[0] += xv * w0.x; acc[1] += xv * w0.y; acc[2] += xv * w0.z; acc[3] += xv * w0.w;
    acc[4] += xv * w1.x; acc[5] += xv * w1.y; acc[6] += xv * w1.z; acc[7] += xv * w1.w;
  }
#pragma unroll
  for (int s = 32; s > 0; s >>= 1) {
#pragma unroll
    for (int n = 0; n < NEXP; ++n) acc[n] += __shfl_down(acc[n], s);
  }
  if (lane == 0) {
    float logit[NEXP];
#pragma unroll
    for (int n = 0; n < NEXP; ++n) logit[n] = acc[n] + br[n];
    int k = topk_p[0]; if (k < 1) k = 1; if (k > NEXP) k = NEXP;
    bool used[NEXP];
#pragma unroll
    for (int n = 0; n < NEXP; ++n) used[n] = false;
    int se[NEXP]; float sw[NEXP];
    for (int j = 0; j < k; ++j) {           // strict > : lowest index wins ties (lax.top_k)
      int bi = 0; float bv = -INFINITY;
      for (int n = 0; n < NEXP; ++n)
        if (!used[n] && logit[n] > bv) { bv = logit[n]; bi = n; }
      used[bi] = true; se[j] = bi; sw[j] = bv;
    }
    float mx = sw[0], sum = 0.f;
    for (int j = 0; j < k; ++j) { sw[j] = expf(sw[j] - mx); sum += sw[j]; }
    float inv = 1.f / sum;
    for (int j = 0; j < k; ++j) {
      int e = se[j];
      int pos = atomicAdd(&counts[e], 1);
      sel_e[t * 8 + j] = e;
      sel_pos[t * 8 + j] = pos;
      sel_w[t * 8 + j] = sw[j] * inv;
    }
  }
}

// ---------------- prefix sums + row->token gather map ----------------
__global__ void prefix_assign_k(const int* __restrict__ counts, int* __restrict__ offsets,
                                const int* __restrict__ sel_e, const int* __restrict__ sel_pos,
                                const int* __restrict__ topk_p, int* __restrict__ row_token) {
  __shared__ int offs[NEXP];
  if (threadIdx.x == 0) {
    int s = 0;
    for (int e = 0; e < NEXP; ++e) { offsets[e] = s; offs[e] = s; s += counts[e]; }
  }
  __syncthreads();
  int k = topk_p[0]; if (k < 1) k = 1; if (k > 8) k = 8;
  for (int i = threadIdx.x; i < TOKENS * k; i += blockDim.x) {
    int t = i / k, j = i - t * k;
    int e = sel_e[t * 8 + j];
    row_token[offs[e] + sel_pos[t * 8 + j]] = t;
  }
}

// ---------------- gather+cast: xg[row] = bf16(x[row_token[row]]) ----------------
__global__ void gather_cast_k(const float* __restrict__ x, const int* __restrict__ row_token,
                              const int* __restrict__ counts, u16* __restrict__ xg) {
  __shared__ int tot_s;
  if (threadIdx.x == 0) {
    int t = 0;
#pragma unroll
    for (int e = 0; e < NEXP; ++e) t += counts[e];
    tot_s = t;
  }
  __syncthreads();
  const int row = blockIdx.x;
  if (row >= tot_s) return;                 // pad rows stay poisoned (finite bf16)
  const float* src = x + (size_t)row_token[row] * EDIM;
  u16* dst = xg + (size_t)row * EDIM;
  const int i = threadIdx.x;                // 256 thr x float4
  float4 v = *(const float4*)(src + i * 4);
  us4 o; o[0] = f2bf(v.x); o[1] = f2bf(v.y); o[2] = f2bf(v.z); o[3] = f2bf(v.w);
  *(us4*)(dst + i * 4) = o;
}

// ------ transpose+downcast one 1024x1024 chunk of W1 and W2 per expert ------
// z<8:  W1t[e][h][ei]  = bf16(W1[e][ei][h0+h])   (in rows ei, stride HDIM)
// z>=8: W2t[e][ep][h]  = bf16(W2[e][h0+h][ep])   (in rows h,  stride EDIM)
__global__ void transpose_k(const float* __restrict__ W1, const float* __restrict__ W2,
                            u16* __restrict__ W1t, u16* __restrict__ W2t, int h0) {
  __shared__ __align__(16) u16 T[64][68];   // +4 pad
  const int z = blockIdx.z;
  const float* in; u16* out; size_t istride;
  if (z < 8) {
    in = W1 + (size_t)z * EDIM * HDIM + h0;                istride = HDIM;
    out = W1t + (size_t)z * 1024 * 1024;
  } else {
    int e = z - 8;
    in = W2 + (size_t)e * HDIM * EDIM + (size_t)h0 * EDIM; istride = EDIM;
    out = W2t + (size_t)e * 1024 * 1024;
  }
  const int r0 = blockIdx.y * 64, c0 = blockIdx.x * 64;
  const int tid = threadIdx.x;
#pragma unroll
  for (int it = 0; it < 4; ++it) {
    int cell = it * 256 + tid;              // 1024 cells: rl(64) x c4(16)
    int rl = cell >> 4, c4 = (cell & 15) * 4;
    float4 v = *(const float4*)(in + (size_t)(r0 + rl) * istride + c0 + c4);
    us4 o; o[0] = f2bf(v.x); o[1] = f2bf(v.y); o[2] = f2bf(v.z); o[3] = f2bf(v.w);
    *(us4*)&T[rl][c4] = o;
  }
  __syncthreads();
#pragma unroll
  for (int it = 0; it < 2; ++it) {
    int cell = it * 256 + tid;              // 512 cells: cl(64) x r8(8)
    int cl = cell >> 3, r8 = (cell & 7) * 8;
    us8 o;
#pragma unroll
    for (int j = 0; j < 8; ++j) o[j] = T[r8 + j][cl];
    *(us8*)(out + (size_t)(c0 + cl) * 1024 + r0 + r8) = o;
  }
}

// ---------------- grouped 128x128x(K=1024) bf16 MFMA GEMM, BK=64 ----------------
// A is dense compact rows (xg for MODE0, hid for MODE1), stride 1024, rows off_e+m.
// LDS: row-major [128 rows][128B], 16B chunk slot XOR-swizzled by row&7 on BOTH
// the global-fetch side and the ds_read side -> coalesced 64B-line staging AND
// conflict-free fragment reads.
template <int MODE>
__global__ __launch_bounds__(256, 2) void gemm_k(
    const u16* __restrict__ A, const u16* __restrict__ Bt, const float* __restrict__ bias,
    const int* __restrict__ counts, const int* __restrict__ offsets,
    u16* __restrict__ hid, float* __restrict__ Y, int h0, int accum) {
  const int e = blockIdx.z;
  const int cnt = counts[e];
  const int m0 = blockIdx.x * 128;
  if (m0 >= cnt) return;
  const int n0 = blockIdx.y * 128;
  const int off_e = offsets[e];

  __shared__ __align__(16) u16 As[128 * 64];  // 16 KB, row stride 64 u16 = 128 B
  __shared__ __align__(16) u16 Bs[128 * 64];

  const int tid = threadIdx.x;
  const int wv = tid >> 6, ln = tid & 63;
  // staging: 8 lanes per row, 16B per lane; chunk slot s holds global chunk s^rl
  const int rl = ln >> 3, sl = ln & 7;
  const int cg = sl ^ rl;                     // swizzled global 16B-chunk index
  const u16* gA = A + ((size_t)(off_e + m0 + wv * 32 + rl)) * 1024 + cg * 8;
  const u16* gB = Bt + ((size_t)e << 20) + ((size_t)(n0 + wv * 32 + rl)) * 1024 + cg * 8;
  u16* lA = As + (wv * 32) * 64;
  u16* lB = Bs + (wv * 32) * 64;

  const int wm = wv >> 1, wn = wv & 1;
  const int quad = ln >> 4, l15 = ln & 15;
  // fragment LDS offsets (u16 units): row*64 + ((ks*4+quad)^(row&7))*8
  int aoff[2][4], boff[2][4];
#pragma unroll
  for (int ks = 0; ks < 2; ++ks) {
#pragma unroll
    for (int mi = 0; mi < 4; ++mi) {
      int ra = wm * 64 + mi * 16 + l15;
      aoff[ks][mi] = ra * 64 + (((ks * 4 + quad) ^ (ra & 7)) * 8);
      int rb = wn * 64 + mi * 16 + l15;
      boff[ks][mi] = rb * 64 + (((ks * 4 + quad) ^ (rb & 7)) * 8);
    }
  }

  f32x4 acc[4][4];
#pragma unroll
  for (int mi = 0; mi < 4; ++mi)
#pragma unroll
    for (int ni = 0; ni < 4; ++ni) acc[mi][ni] = (f32x4){0.f, 0.f, 0.f, 0.f};

  for (int k0 = 0; k0 < 1024; k0 += 64) {
    __syncthreads();                        // prev iter's LDS reads done
#pragma unroll
    for (int j = 0; j < 4; ++j) async16(lA + j * 8 * 64, gA + k0 + (size_t)j * 8 * 1024);
#pragma unroll
    for (int j = 0; j < 4; ++j) async16(lB + j * 8 * 64, gB + k0 + (size_t)j * 8 * 1024);
    __syncthreads();                        // drains vmcnt -> LDS ready
#pragma unroll
    for (int ks = 0; ks < 2; ++ks) {
      bf16x8 a[4], b[4];
#pragma unroll
      for (int mi = 0; mi < 4; ++mi) a[mi] = *(const bf16x8*)(As + aoff[ks][mi]);
#pragma unroll
      for (int ni = 0; ni < 4; ++ni) b[ni] = *(const bf16x8*)(Bs + boff[ks][ni]);
#pragma unroll
      for (int mi = 0; mi < 4; ++mi)
#pragma unroll
        for (int ni = 0; ni < 4; ++ni)
          acc[mi][ni] = __builtin_amdgcn_mfma_f32_16x16x32_bf16(a[mi], b[ni], acc[mi][ni], 0, 0, 0);
    }
  }

  // epilogue: D row = quad*4+r, col = l15 (m89/m91-verified layout)
#pragma unroll
  for (int mi = 0; mi < 4; ++mi) {
    const int mbase = m0 + wm * 64 + mi * 16 + quad * 4;
#pragma unroll
    for (int ni = 0; ni < 4; ++ni) {
      const int nloc = n0 + wn * 64 + ni * 16 + l15;
      float bv;
      if (MODE == 0) bv = bias[e * HDIM + h0 + nloc];
      else           bv = accum ? 0.f : bias[e * EDIM + nloc];
#pragma unroll
      for (int r = 0; r < 4; ++r) {
        const int m = mbase + r;
        if (m < cnt) {
          float v = acc[mi][ni][r] + bv;
          if (MODE == 0) {
            v = 0.5f * v * (1.f + erff(v * 0.70710678118654752f));  // exact gelu
            hid[(size_t)(off_e + m) * HC + nloc] = f2bf(v);
          } else {
            size_t yi = (size_t)(off_e + m) * EDIM + nloc;
            Y[yi] = accum ? (Y[yi] + v) : v;
          }
        }
      }
    }
  }
}

// ---------------- weighted combine over top-k rows ----------------
__global__ void combine_k(const float* __restrict__ Y, const int* __restrict__ sel_e,
                          const int* __restrict__ sel_pos, const float* __restrict__ sel_w,
                          const int* __restrict__ offsets, const int* __restrict__ topk_p,
                          float* __restrict__ out) {
  const int t = blockIdx.x;
  const int tid = threadIdx.x;              // 256 thr x 4 floats
  int k = topk_p[0]; if (k < 1) k = 1; if (k > 8) k = 8;
  float a0 = 0.f, a1 = 0.f, a2 = 0.f, a3 = 0.f;
  for (int j = 0; j < k; ++j) {
    const int e = sel_e[t * 8 + j];
    const float w = sel_w[t * 8 + j];
    const size_t row = (size_t)offsets[e] + sel_pos[t * 8 + j];
    const float4 v = *(const float4*)(Y + row * EDIM + tid * 4);
    a0 += w * v.x; a1 += w * v.y; a2 += w * v.z; a3 += w * v.w;
  }
  float4 o; o.x = a0; o.y = a1; o.z = a2; o.w = a3;
  *(float4*)(out + (size_t)t * EDIM + tid * 4) = o;
}

extern "C" void kernel_launch(void* const* d_in, const int* in_sizes, int n_in,
                              void* d_out, int out_size, void* d_ws, size_t ws_size,
                              hipStream_t stream) {
  const float* x   = (const float*)d_in[0];
  const float* Wr  = (const float*)d_in[1];
  const float* br  = (const float*)d_in[2];
  const float* W1  = (const float*)d_in[3];
  const float* b1  = (const float*)d_in[4];
  const float* W2  = (const float*)d_in[5];
  const float* b2  = (const float*)d_in[6];
  const int* topk  = (const int*)d_in[7];
  float* out = (float*)d_out;

  char* ws = (char*)d_ws;
  size_t o = 0;
  auto alloc = [&](size_t bytes) -> char* {
    char* p = ws + o; o += (bytes + 255) & ~(size_t)255; return p;
  };
  int*   counts    = (int*)alloc(NEXP * 4);
  int*   offsets   = (int*)alloc(NEXP * 4);
  int*   sel_e     = (int*)alloc((size_t)TOKENS * 8 * 4);
  int*   sel_pos   = (int*)alloc((size_t)TOKENS * 8 * 4);
  float* sel_w     = (float*)alloc((size_t)TOKENS * 8 * 4);
  int*   row_token = (int*)alloc((size_t)TOKENS * 8 * 4);
  u16*   xg        = (u16*)alloc((size_t)(MAXROWS + ROWPAD) * EDIM * 2);  //  17.0 MB
  u16*   W1t       = (u16*)alloc((size_t)NEXP * 1024 * 1024 * 2);         //  16.8 MB
  u16*   W2t       = (u16*)alloc((size_t)NEXP * 1024 * 1024 * 2);         //  16.8 MB
  u16*   hid       = (u16*)alloc((size_t)(MAXROWS + ROWPAD) * HC * 2);    //  17.0 MB
  float* Y         = (float*)alloc((size_t)MAXROWS * EDIM * 4);           //  33.5 MB
  // total ~= 101 MB of ws

  hipMemsetAsync(counts, 0, NEXP * sizeof(int), stream);
  router_k<<<dim3(TOKENS), dim3(64), 0, stream>>>(x, Wr, br, topk,
                                                  counts, sel_e, sel_pos, sel_w);
  prefix_assign_k<<<dim3(1), dim3(256), 0, stream>>>(counts, offsets, sel_e, sel_pos,
                                                     topk, row_token);
  gather_cast_k<<<dim3(MAXROWS), dim3(256), 0, stream>>>(x, row_token, counts, xg);
  for (int c = 0; c < NCHUNK; ++c) {
    const int h0 = c * HC;
    transpose_k<<<dim3(16, 16, 16), dim3(256), 0, stream>>>(W1, W2, W1t, W2t, h0);
    gemm_k<0><<<dim3(32, 8, 8), dim3(256), 0, stream>>>(xg, W1t, b1, counts, offsets,
                                                        hid, nullptr, h0, 0);
    gemm_k<1><<<dim3(32, 8, 8), dim3(256), 0, stream>>>(hid, W2t, b2, counts, offsets,
                                                        nullptr, Y, h0, c > 0 ? 1 : 0);
  }
  combine_k<<<dim3(TOKENS), dim3(256), 0, stream>>>(Y, sel_e, sel_pos, sel_w,
                                                    offsets, topk, out);
}

// Round 4
// 982.554 us; speedup vs baseline: 1.8472x; 1.2212x over previous
//
#include <hip/hip_runtime.h>
#include <hip/hip_bf16.h>
#include <cmath>
#include <cstdint>

// SparseMoE: B=2,S=2048 -> 4096 tokens, E=1024, N=8 experts, H=4096, top_k=2.
// fp32 I/O; internally bf16 MFMA grouped GEMM over the top-k expert rows only.
// R4: register-staged (buffer_load -> ds_write) double-buffered K-loop with
// XOR-swizzled LDS on both write+read sides; compact tile-map grid (no dead
// blocks). R3 was VMEM-transaction-bound: XOR on the global side of
// global_load_lds defeated coalescing, and 75% of blocks were dead.

typedef unsigned short u16;
typedef __attribute__((ext_vector_type(8))) short bf16x8;   // MFMA A/B frag (4 VGPR)
typedef __attribute__((ext_vector_type(4))) float f32x4;    // MFMA C/D frag
typedef __attribute__((ext_vector_type(8))) unsigned short us8;
typedef __attribute__((ext_vector_type(4))) unsigned short us4;

#define TOKENS  4096
#define EDIM    1024
#define NEXP    8
#define HDIM    4096
#define HC      1024      // H chunk
#define NCHUNK  4
#define MAXROWS 8192      // top_k(=2) * TOKENS
#define ROWPAD  128       // tail staging may read past cnt; keep in-bounds
#define MAXTILES 72       // sum ceil(cnt_e/128) <= 64 + 7

__device__ __forceinline__ u16 f2bf(float f) {
  __hip_bfloat16 h = __float2bfloat16(f);   // RNE
  return *reinterpret_cast<u16*>(&h);
}

// ---------------- router: logits, top-k, softmax, expert lists ----------------
__global__ void router_k(const float* __restrict__ x, const float* __restrict__ Wr,
                         const float* __restrict__ br, const int* __restrict__ topk_p,
                         int* __restrict__ counts, int* __restrict__ sel_e,
                         int* __restrict__ sel_pos, float* __restrict__ sel_w) {
  const int t = blockIdx.x;
  const int lane = threadIdx.x;             // 64 threads = 1 wave
  float acc[NEXP];
#pragma unroll
  for (int n = 0; n < NEXP; ++n) acc[n] = 0.f;
  const float* xr = x + (size_t)t * EDIM;
  for (int ei = lane; ei < EDIM; ei += 64) {
    float xv = xr[ei];
    float4 w0 = *(const float4*)(Wr + ei * NEXP);
    float4 w1 = *(const float4*)(Wr + ei * NEXP + 4);
    acc[0] += xv * w0.x; acc[1] += xv * w0.y; acc[2] += xv * w0.z; acc[3] += xv * w0.w;
    acc[4] += xv * w1.x; acc[5] += xv * w1.y; acc[6] += xv * w1.z; acc[7] += xv * w1.w;
  }
#pragma unroll
  for (int s = 32; s > 0; s >>= 1) {
#pragma unroll
    for (int n = 0; n < NEXP; ++n) acc[n] += __shfl_down(acc[n], s);
  }
  if (lane == 0) {
    float logit[NEXP];
#pragma unroll
    for (int n = 0; n < NEXP; ++n) logit[n] = acc[n] + br[n];
    int k = topk_p[0]; if (k < 1) k = 1; if (k > NEXP) k = NEXP;
    bool used[NEXP];
#pragma unroll
    for (int n = 0; n < NEXP; ++n) used[n] = false;
    int se[NEXP]; float sw[NEXP];
    for (int j = 0; j < k; ++j) {           // strict > : lowest index wins ties (lax.top_k)
      int bi = 0; float bv = -INFINITY;
      for (int n = 0; n < NEXP; ++n)
        if (!used[n] && logit[n] > bv) { bv = logit[n]; bi = n; }
      used[bi] = true; se[j] = bi; sw[j] = bv;
    }
    float mx = sw[0], sum = 0.f;
    for (int j = 0; j < k; ++j) { sw[j] = expf(sw[j] - mx); sum += sw[j]; }
    float inv = 1.f / sum;
    for (int j = 0; j < k; ++j) {
      int e = se[j];
      int pos = atomicAdd(&counts[e], 1);
      sel_e[t * 8 + j] = e;
      sel_pos[t * 8 + j] = pos;
      sel_w[t * 8 + j] = sw[j] * inv;
    }
  }
}

// ------------- prefix sums + row->token map + compact tile map -------------
__global__ void prefix_assign_k(const int* __restrict__ counts, int* __restrict__ offsets,
                                const int* __restrict__ sel_e, const int* __restrict__ sel_pos,
                                const int* __restrict__ topk_p, int* __restrict__ row_token,
                                int* __restrict__ tmap) {
  __shared__ int offs[NEXP];
  if (threadIdx.x == 0) {
    int s = 0;
    for (int e = 0; e < NEXP; ++e) { offsets[e] = s; offs[e] = s; s += counts[e]; }
    int nt = 0;
    for (int e = 0; e < NEXP; ++e) {
      int nb = (counts[e] + 127) >> 7;
      for (int b = 0; b < nb && nt < MAXTILES; ++b) tmap[nt++] = (e << 16) | b;
    }
    for (; nt < MAXTILES; ++nt) tmap[nt] = -1;
  }
  __syncthreads();
  int k = topk_p[0]; if (k < 1) k = 1; if (k > 8) k = 8;
  for (int i = threadIdx.x; i < TOKENS * k; i += blockDim.x) {
    int t = i / k, j = i - t * k;
    int e = sel_e[t * 8 + j];
    row_token[offs[e] + sel_pos[t * 8 + j]] = t;
  }
}

// ---------------- gather+cast: xg[row] = bf16(x[row_token[row]]) ----------------
__global__ void gather_cast_k(const float* __restrict__ x, const int* __restrict__ row_token,
                              const int* __restrict__ counts, u16* __restrict__ xg) {
  __shared__ int tot_s;
  if (threadIdx.x == 0) {
    int t = 0;
#pragma unroll
    for (int e = 0; e < NEXP; ++e) t += counts[e];
    tot_s = t;
  }
  __syncthreads();
  const int row = blockIdx.x;
  if (row >= tot_s) return;                 // pad rows stay poisoned (finite bf16)
  const float* src = x + (size_t)row_token[row] * EDIM;
  u16* dst = xg + (size_t)row * EDIM;
  const int i = threadIdx.x;                // 256 thr x float4
  float4 v = *(const float4*)(src + i * 4);
  us4 o; o[0] = f2bf(v.x); o[1] = f2bf(v.y); o[2] = f2bf(v.z); o[3] = f2bf(v.w);
  *(us4*)(dst + i * 4) = o;
}

// ------ transpose+downcast one 1024x1024 chunk of W1 and W2 per expert ------
__global__ void transpose_k(const float* __restrict__ W1, const float* __restrict__ W2,
                            u16* __restrict__ W1t, u16* __restrict__ W2t, int h0) {
  __shared__ __align__(16) u16 T[64][68];   // +4 pad
  const int z = blockIdx.z;
  const float* in; u16* out; size_t istride;
  if (z < 8) {
    in = W1 + (size_t)z * EDIM * HDIM + h0;                istride = HDIM;
    out = W1t + (size_t)z * 1024 * 1024;
  } else {
    int e = z - 8;
    in = W2 + (size_t)e * HDIM * EDIM + (size_t)h0 * EDIM; istride = EDIM;
    out = W2t + (size_t)e * 1024 * 1024;
  }
  const int r0 = blockIdx.y * 64, c0 = blockIdx.x * 64;
  const int tid = threadIdx.x;
#pragma unroll
  for (int it = 0; it < 4; ++it) {
    int cell = it * 256 + tid;              // 1024 cells: rl(64) x c4(16)
    int rl = cell >> 4, c4 = (cell & 15) * 4;
    float4 v = *(const float4*)(in + (size_t)(r0 + rl) * istride + c0 + c4);
    us4 o; o[0] = f2bf(v.x); o[1] = f2bf(v.y); o[2] = f2bf(v.z); o[3] = f2bf(v.w);
    *(us4*)&T[rl][c4] = o;
  }
  __syncthreads();
#pragma unroll
  for (int it = 0; it < 2; ++it) {
    int cell = it * 256 + tid;              // 512 cells: cl(64) x r8(8)
    int cl = cell >> 3, r8 = (cell & 7) * 8;
    us8 o;
#pragma unroll
    for (int j = 0; j < 8; ++j) o[j] = T[r8 + j][cl];
    *(us8*)(out + (size_t)(c0 + cl) * 1024 + r0 + r8) = o;
  }
}

// -------- grouped 128x128x(K=1024) bf16 MFMA GEMM, BK=64, dbuf pipeline --------
// A dense compact rows (xg MODE0 / hid MODE1), stride 1024. Per iter:
//   barrier; buffer_load k+1 -> regs; ds_read+MFMA on buf[k&1]; ds_write k+1.
// LDS row-major [128][64 u16], 16B chunk slot XORed with row&7 (write+read match).
template <int MODE>
__global__ __launch_bounds__(256, 2) void gemm_k(
    const u16* __restrict__ A, const u16* __restrict__ Bt, const float* __restrict__ bias,
    const int* __restrict__ counts, const int* __restrict__ offsets,
    const int* __restrict__ tmap,
    u16* __restrict__ hid, float* __restrict__ Y, int h0, int accum) {
  const int tv = tmap[blockIdx.x];
  if (tv < 0) return;
  const int e = tv >> 16;
  const int m0 = (tv & 0xffff) * 128;
  const int cnt = counts[e];
  const int off_e = offsets[e];
  const int n0 = blockIdx.y * 128;

  __shared__ __align__(16) u16 As[2][8192];   // 2 x 16 KB
  __shared__ __align__(16) u16 Bs[2][8192];

  const int tid = threadIdx.x;
  const int wv = tid >> 6, ln = tid & 63;

  // staging ownership: thread -> (row r_ + 32*p, chunk c_), 4 passes each for A,B
  const int r_ = tid >> 3, c_ = tid & 7;            // 32 rows x 8 chunks per pass
  const int swz = (c_ ^ (r_ & 7)) * 8;              // u16 offset of swizzled chunk
  const u16* gA = A + (size_t)(off_e + m0 + r_) * 1024 + c_ * 8;
  const u16* gB = Bt + ((size_t)e << 20) + (size_t)(n0 + r_) * 1024 + c_ * 8;
  const int lw = r_ * 64 + swz;                     // LDS write base (u16)

  const int wm = wv >> 1, wn = wv & 1;
  const int quad = ln >> 4, l15 = ln & 15;
  int aoff[2][4], boff[2][4];
#pragma unroll
  for (int ks = 0; ks < 2; ++ks) {
#pragma unroll
    for (int mi = 0; mi < 4; ++mi) {
      int ra = wm * 64 + mi * 16 + l15;
      aoff[ks][mi] = ra * 64 + (((ks * 4 + quad) ^ (ra & 7)) * 8);
      int rb = wn * 64 + mi * 16 + l15;
      boff[ks][mi] = rb * 64 + (((ks * 4 + quad) ^ (rb & 7)) * 8);
    }
  }

  f32x4 acc[4][4];
#pragma unroll
  for (int mi = 0; mi < 4; ++mi)
#pragma unroll
    for (int ni = 0; ni < 4; ++ni) acc[mi][ni] = (f32x4){0.f, 0.f, 0.f, 0.f};

  us8 ra[4], rb[4];
  // prologue: load k=0, write buf 0
#pragma unroll
  for (int p = 0; p < 4; ++p) {
    ra[p] = *(const us8*)(gA + (size_t)p * 32 * 1024);
    rb[p] = *(const us8*)(gB + (size_t)p * 32 * 1024);
  }
#pragma unroll
  for (int p = 0; p < 4; ++p) {
    *(us8*)(&As[0][lw + p * 2048]) = ra[p];
    *(us8*)(&Bs[0][lw + p * 2048]) = rb[p];
  }

  for (int it = 0; it < 16; ++it) {
    __syncthreads();                         // buf[it&1] ready; buf[it&1^1] free
    const int cur = it & 1;
    if (it + 1 < 16) {
      const int k1 = (it + 1) * 64;
#pragma unroll
      for (int p = 0; p < 4; ++p) {
        ra[p] = *(const us8*)(gA + k1 + (size_t)p * 32 * 1024);
        rb[p] = *(const us8*)(gB + k1 + (size_t)p * 32 * 1024);
      }
    }
#pragma unroll
    for (int ks = 0; ks < 2; ++ks) {
      bf16x8 a[4], b[4];
#pragma unroll
      for (int mi = 0; mi < 4; ++mi) a[mi] = *(const bf16x8*)(&As[cur][aoff[ks][mi]]);
#pragma unroll
      for (int ni = 0; ni < 4; ++ni) b[ni] = *(const bf16x8*)(&Bs[cur][boff[ks][ni]]);
#pragma unroll
      for (int mi = 0; mi < 4; ++mi)
#pragma unroll
        for (int ni = 0; ni < 4; ++ni)
          acc[mi][ni] = __builtin_amdgcn_mfma_f32_16x16x32_bf16(a[mi], b[ni], acc[mi][ni], 0, 0, 0);
    }
    if (it + 1 < 16) {
      const int nxt = cur ^ 1;
#pragma unroll
      for (int p = 0; p < 4; ++p) {
        *(us8*)(&As[nxt][lw + p * 2048]) = ra[p];
        *(us8*)(&Bs[nxt][lw + p * 2048]) = rb[p];
      }
    }
  }

  // epilogue: D row = quad*4+r, col = l15 (m89/m91-verified layout)
#pragma unroll
  for (int mi = 0; mi < 4; ++mi) {
    const int mbase = m0 + wm * 64 + mi * 16 + quad * 4;
#pragma unroll
    for (int ni = 0; ni < 4; ++ni) {
      const int nloc = n0 + wn * 64 + ni * 16 + l15;
      float bv;
      if (MODE == 0) bv = bias[e * HDIM + h0 + nloc];
      else           bv = accum ? 0.f : bias[e * EDIM + nloc];
#pragma unroll
      for (int r = 0; r < 4; ++r) {
        const int m = mbase + r;
        if (m < cnt) {
          float v = acc[mi][ni][r] + bv;
          if (MODE == 0) {
            v = 0.5f * v * (1.f + erff(v * 0.70710678118654752f));  // exact gelu
            hid[(size_t)(off_e + m) * HC + nloc] = f2bf(v);
          } else {
            size_t yi = (size_t)(off_e + m) * EDIM + nloc;
            Y[yi] = accum ? (Y[yi] + v) : v;
          }
        }
      }
    }
  }
}

// ---------------- weighted combine over top-k rows ----------------
__global__ void combine_k(const float* __restrict__ Y, const int* __restrict__ sel_e,
                          const int* __restrict__ sel_pos, const float* __restrict__ sel_w,
                          const int* __restrict__ offsets, const int* __restrict__ topk_p,
                          float* __restrict__ out) {
  const int t = blockIdx.x;
  const int tid = threadIdx.x;              // 256 thr x 4 floats
  int k = topk_p[0]; if (k < 1) k = 1; if (k > 8) k = 8;
  float a0 = 0.f, a1 = 0.f, a2 = 0.f, a3 = 0.f;
  for (int j = 0; j < k; ++j) {
    const int e = sel_e[t * 8 + j];
    const float w = sel_w[t * 8 + j];
    const size_t row = (size_t)offsets[e] + sel_pos[t * 8 + j];
    const float4 v = *(const float4*)(Y + row * EDIM + tid * 4);
    a0 += w * v.x; a1 += w * v.y; a2 += w * v.z; a3 += w * v.w;
  }
  float4 o; o.x = a0; o.y = a1; o.z = a2; o.w = a3;
  *(float4*)(out + (size_t)t * EDIM + tid * 4) = o;
}

extern "C" void kernel_launch(void* const* d_in, const int* in_sizes, int n_in,
                              void* d_out, int out_size, void* d_ws, size_t ws_size,
                              hipStream_t stream) {
  const float* x   = (const float*)d_in[0];
  const float* Wr  = (const float*)d_in[1];
  const float* br  = (const float*)d_in[2];
  const float* W1  = (const float*)d_in[3];
  const float* b1  = (const float*)d_in[4];
  const float* W2  = (const float*)d_in[5];
  const float* b2  = (const float*)d_in[6];
  const int* topk  = (const int*)d_in[7];
  float* out = (float*)d_out;

  char* ws = (char*)d_ws;
  size_t o = 0;
  auto alloc = [&](size_t bytes) -> char* {
    char* p = ws + o; o += (bytes + 255) & ~(size_t)255; return p;
  };
  int*   counts    = (int*)alloc(NEXP * 4);
  int*   offsets   = (int*)alloc(NEXP * 4);
  int*   tmap      = (int*)alloc(MAXTILES * 4);
  int*   sel_e     = (int*)alloc((size_t)TOKENS * 8 * 4);
  int*   sel_pos   = (int*)alloc((size_t)TOKENS * 8 * 4);
  float* sel_w     = (float*)alloc((size_t)TOKENS * 8 * 4);
  int*   row_token = (int*)alloc((size_t)TOKENS * 8 * 4);
  u16*   xg        = (u16*)alloc((size_t)(MAXROWS + ROWPAD) * EDIM * 2);  //  17.0 MB
  u16*   W1t       = (u16*)alloc((size_t)NEXP * 1024 * 1024 * 2);         //  16.8 MB
  u16*   W2t       = (u16*)alloc((size_t)NEXP * 1024 * 1024 * 2);         //  16.8 MB
  u16*   hid       = (u16*)alloc((size_t)(MAXROWS + ROWPAD) * HC * 2);    //  17.0 MB
  float* Y         = (float*)alloc((size_t)MAXROWS * EDIM * 4);           //  33.5 MB
  // total ~= 101 MB of ws

  hipMemsetAsync(counts, 0, NEXP * sizeof(int), stream);
  router_k<<<dim3(TOKENS), dim3(64), 0, stream>>>(x, Wr, br, topk,
                                                  counts, sel_e, sel_pos, sel_w);
  prefix_assign_k<<<dim3(1), dim3(256), 0, stream>>>(counts, offsets, sel_e, sel_pos,
                                                     topk, row_token, tmap);
  gather_cast_k<<<dim3(MAXROWS), dim3(256), 0, stream>>>(x, row_token, counts, xg);
  for (int c = 0; c < NCHUNK; ++c) {
    const int h0 = c * HC;
    transpose_k<<<dim3(16, 16, 16), dim3(256), 0, stream>>>(W1, W2, W1t, W2t, h0);
    gemm_k<0><<<dim3(MAXTILES, 8), dim3(256), 0, stream>>>(xg, W1t, b1, counts, offsets,
                                                           tmap, hid, nullptr, h0, 0);
    gemm_k<1><<<dim3(MAXTILES, 8), dim3(256), 0, stream>>>(hid, W2t, b2, counts, offsets,
                                                           tmap, nullptr, Y, h0,
                                                           c > 0 ? 1 : 0);
  }
  combine_k<<<dim3(TOKENS), dim3(256), 0, stream>>>(Y, sel_e, sel_pos, sel_w,
                                                    offsets, topk, out);
}

// Round 5
// 849.535 us; speedup vs baseline: 2.1364x; 1.1566x over previous
//
#include <hip/hip_runtime.h>
#include <hip/hip_bf16.h>
#include <cmath>
#include <cstdint>

// SparseMoE: B=2,S=2048 -> 4096 tokens, E=1024, N=8 experts, H=4096, top_k=2.
// fp32 I/O; internally bf16 MFMA grouped GEMM over the top-k expert rows only.
// R5: (1) atomic-free router (R4's 110us was 8192 same-cache-line device atomics),
//     (2) queue-2 register prefetch in GEMM (loads issued 2 iters ahead),
//     (3) n0-major grid -> per-XCD B-row L2 residency.

typedef unsigned short u16;
typedef __attribute__((ext_vector_type(8))) short bf16x8;   // MFMA A/B frag (4 VGPR)
typedef __attribute__((ext_vector_type(4))) float f32x4;    // MFMA C/D frag
typedef __attribute__((ext_vector_type(8))) unsigned short us8;
typedef __attribute__((ext_vector_type(4))) unsigned short us4;

#define TOKENS  4096
#define EDIM    1024
#define NEXP    8
#define HDIM    4096
#define HC      1024      // H chunk
#define NCHUNK  4
#define MAXROWS 8192      // top_k(=2) * TOKENS
#define ROWPAD  128       // tail staging may read past cnt; keep in-bounds
#define MAXTILES 72       // sum ceil(cnt_e/128) <= 64 + 7
#define RBLK    1024      // router blocks (4 tokens each)

__device__ __forceinline__ u16 f2bf(float f) {
  __hip_bfloat16 h = __float2bfloat16(f);   // RNE
  return *reinterpret_cast<u16*>(&h);
}
__device__ __forceinline__ int clampk(int k) {
  return k < 1 ? 1 : (k > 8 ? 8 : k);
}

// ---------- router: logits + top-k + softmax + block-local hist (NO atomics) ----------
__global__ void router_k(const float* __restrict__ x, const float* __restrict__ Wr,
                         const float* __restrict__ br, const int* __restrict__ topk_p,
                         int* __restrict__ sel_e, float* __restrict__ sel_w,
                         int* __restrict__ sel_lpos, int* __restrict__ hist_blk) {
  __shared__ int wsel[4][8];
  const int blk = blockIdx.x;
  const int tid = threadIdx.x;
  const int wv = tid >> 6, ln = tid & 63;
  const int t = blk * 4 + wv;
  const int k = clampk(topk_p[0]);
  float acc[NEXP];
#pragma unroll
  for (int n = 0; n < NEXP; ++n) acc[n] = 0.f;
  const float* xr = x + (size_t)t * EDIM;
  for (int ei = ln; ei < EDIM; ei += 64) {
    float xv = xr[ei];
    float4 w0 = *(const float4*)(Wr + ei * NEXP);
    float4 w1 = *(const float4*)(Wr + ei * NEXP + 4);
    acc[0] += xv * w0.x; acc[1] += xv * w0.y; acc[2] += xv * w0.z; acc[3] += xv * w0.w;
    acc[4] += xv * w1.x; acc[5] += xv * w1.y; acc[6] += xv * w1.z; acc[7] += xv * w1.w;
  }
#pragma unroll
  for (int s = 32; s > 0; s >>= 1) {
#pragma unroll
    for (int n = 0; n < NEXP; ++n) acc[n] += __shfl_down(acc[n], s);
  }
  if (ln == 0) {
    float logit[NEXP];
#pragma unroll
    for (int n = 0; n < NEXP; ++n) logit[n] = acc[n] + br[n];
    bool used[NEXP];
#pragma unroll
    for (int n = 0; n < NEXP; ++n) used[n] = false;
    int se[NEXP]; float sw[NEXP];
    for (int j = 0; j < k; ++j) {           // strict > : lowest index wins ties (lax.top_k)
      int bi = 0; float bv = -INFINITY;
      for (int n = 0; n < NEXP; ++n)
        if (!used[n] && logit[n] > bv) { bv = logit[n]; bi = n; }
      used[bi] = true; se[j] = bi; sw[j] = bv;
    }
    float mx = sw[0], sum = 0.f;
    for (int j = 0; j < k; ++j) { sw[j] = expf(sw[j] - mx); sum += sw[j]; }
    float inv = 1.f / sum;
    for (int j = 0; j < k; ++j) {
      sel_e[t * 8 + j] = se[j];
      sel_w[t * 8 + j] = sw[j] * inv;
      wsel[wv][j] = se[j];
    }
  }
  __syncthreads();
  if (tid == 0) {                           // 8 selections: trivial serial, deterministic
    int h[NEXP];
#pragma unroll
    for (int e = 0; e < NEXP; ++e) h[e] = 0;
    for (int w = 0; w < 4; ++w)
      for (int j = 0; j < k; ++j) {
        int e = wsel[w][j];
        sel_lpos[(blk * 4 + w) * 8 + j] = h[e]++;
      }
#pragma unroll
    for (int e = 0; e < NEXP; ++e) hist_blk[blk * NEXP + e] = h[e];
  }
}

// ---------- scan: per-expert exclusive scan over 1024 block hists ----------
__global__ void scan_k(const int* __restrict__ hist_blk, int* __restrict__ counts,
                       int* __restrict__ offsets, int* __restrict__ blk_base,
                       int* __restrict__ tmap) {
  __shared__ int sc[NEXP][257];
  __shared__ int offs[NEXP];
  const int tid = threadIdx.x;              // 256 threads, 4 hist rows each
  int h[4][NEXP], part[NEXP];
#pragma unroll
  for (int e = 0; e < NEXP; ++e) part[e] = 0;
#pragma unroll
  for (int r = 0; r < 4; ++r) {
    const int row = tid * 4 + r;
#pragma unroll
    for (int e = 0; e < NEXP; ++e) { h[r][e] = hist_blk[row * NEXP + e]; part[e] += h[r][e]; }
  }
#pragma unroll
  for (int e = 0; e < NEXP; ++e) sc[e][tid] = part[e];
  __syncthreads();
  for (int d = 1; d < 256; d <<= 1) {       // Hillis-Steele inclusive scan x8
    int v[NEXP];
#pragma unroll
    for (int e = 0; e < NEXP; ++e) v[e] = (tid >= d) ? sc[e][tid - d] : 0;
    __syncthreads();
#pragma unroll
    for (int e = 0; e < NEXP; ++e) sc[e][tid] += v[e];
    __syncthreads();
  }
  if (tid == 0) {
    int s = 0;
    for (int e = 0; e < NEXP; ++e) {
      int tot = sc[e][255];
      offsets[e] = s; offs[e] = s; counts[e] = tot; s += tot;
    }
    int nt = 0;
    for (int e = 0; e < NEXP; ++e) {
      int nb = (counts[e] + 127) >> 7;
      for (int b = 0; b < nb && nt < MAXTILES; ++b) tmap[nt++] = (e << 16) | b;
    }
    for (; nt < MAXTILES; ++nt) tmap[nt] = -1;
  }
  __syncthreads();
#pragma unroll
  for (int e = 0; e < NEXP; ++e) {
    int run = offs[e] + sc[e][tid] - part[e];   // absolute exclusive base
#pragma unroll
    for (int r = 0; r < 4; ++r) {
      blk_base[(tid * 4 + r) * NEXP + e] = run;
      run += h[r][e];
    }
  }
}

// ---------- finalize: absolute positions + row->token scatter ----------
__global__ void finalize_k(const int* __restrict__ sel_e, const int* __restrict__ sel_lpos,
                           const int* __restrict__ blk_base, const int* __restrict__ topk_p,
                           int* __restrict__ sel_pos, int* __restrict__ row_token) {
  const int k = clampk(topk_p[0]);
  const int i = blockIdx.x * 256 + threadIdx.x;
  if (i >= TOKENS * k) return;
  const int t = i / k, j = i - t * k;
  const int e = sel_e[t * 8 + j];
  const int pos = blk_base[(t >> 2) * NEXP + e] + sel_lpos[t * 8 + j];
  sel_pos[t * 8 + j] = pos;                 // absolute compact-row index
  row_token[pos] = t;
}

// ---------------- gather+cast: xg[row] = bf16(x[row_token[row]]) ----------------
__global__ void gather_cast_k(const float* __restrict__ x, const int* __restrict__ row_token,
                              const int* __restrict__ counts, u16* __restrict__ xg) {
  __shared__ int tot_s;
  if (threadIdx.x == 0) {
    int t = 0;
#pragma unroll
    for (int e = 0; e < NEXP; ++e) t += counts[e];
    tot_s = t;
  }
  __syncthreads();
  const int row = blockIdx.x;
  if (row >= tot_s) return;                 // pad rows stay poisoned (finite bf16)
  const float* src = x + (size_t)row_token[row] * EDIM;
  u16* dst = xg + (size_t)row * EDIM;
  const int i = threadIdx.x;                // 256 thr x float4
  float4 v = *(const float4*)(src + i * 4);
  us4 o; o[0] = f2bf(v.x); o[1] = f2bf(v.y); o[2] = f2bf(v.z); o[3] = f2bf(v.w);
  *(us4*)(dst + i * 4) = o;
}

// ------ transpose+downcast one 1024x1024 chunk of W1 and W2 per expert ------
__global__ void transpose_k(const float* __restrict__ W1, const float* __restrict__ W2,
                            u16* __restrict__ W1t, u16* __restrict__ W2t, int h0) {
  __shared__ __align__(16) u16 T[64][68];   // +4 pad
  const int z = blockIdx.z;
  const float* in; u16* out; size_t istride;
  if (z < 8) {
    in = W1 + (size_t)z * EDIM * HDIM + h0;                istride = HDIM;
    out = W1t + (size_t)z * 1024 * 1024;
  } else {
    int e = z - 8;
    in = W2 + (size_t)e * HDIM * EDIM + (size_t)h0 * EDIM; istride = EDIM;
    out = W2t + (size_t)e * 1024 * 1024;
  }
  const int r0 = blockIdx.y * 64, c0 = blockIdx.x * 64;
  const int tid = threadIdx.x;
#pragma unroll
  for (int it = 0; it < 4; ++it) {
    int cell = it * 256 + tid;              // 1024 cells: rl(64) x c4(16)
    int rl = cell >> 4, c4 = (cell & 15) * 4;
    float4 v = *(const float4*)(in + (size_t)(r0 + rl) * istride + c0 + c4);
    us4 o; o[0] = f2bf(v.x); o[1] = f2bf(v.y); o[2] = f2bf(v.z); o[3] = f2bf(v.w);
    *(us4*)&T[rl][c4] = o;
  }
  __syncthreads();
#pragma unroll
  for (int it = 0; it < 2; ++it) {
    int cell = it * 256 + tid;              // 512 cells: cl(64) x r8(8)
    int cl = cell >> 3, r8 = (cell & 7) * 8;
    us8 o;
#pragma unroll
    for (int j = 0; j < 8; ++j) o[j] = T[r8 + j][cl];
    *(us8*)(out + (size_t)(c0 + cl) * 1024 + r0 + r8) = o;
  }
}

// ---------------- GEMM helpers ----------------
__device__ __forceinline__ void ld8(const u16* gA, const u16* gB, int kblk, us8 q[8]) {
#pragma unroll
  for (int p = 0; p < 4; ++p) {
    q[p]     = *(const us8*)(gA + kblk * 64 + (size_t)p * 32 * 1024);
    q[4 + p] = *(const us8*)(gB + kblk * 64 + (size_t)p * 32 * 1024);
  }
}
__device__ __forceinline__ void wr8(u16* As_b, u16* Bs_b, int lw, const us8 q[8]) {
#pragma unroll
  for (int p = 0; p < 4; ++p) {
    *(us8*)(As_b + lw + p * 2048) = q[p];
    *(us8*)(Bs_b + lw + p * 2048) = q[4 + p];
  }
}
__device__ __forceinline__ void mfma_step(const u16* As_b, const u16* Bs_b,
                                          const int aoff[2][4], const int boff[2][4],
                                          f32x4 acc[4][4]) {
#pragma unroll
  for (int ks = 0; ks < 2; ++ks) {
    bf16x8 a[4], b[4];
#pragma unroll
    for (int mi = 0; mi < 4; ++mi) a[mi] = *(const bf16x8*)(As_b + aoff[ks][mi]);
#pragma unroll
    for (int ni = 0; ni < 4; ++ni) b[ni] = *(const bf16x8*)(Bs_b + boff[ks][ni]);
#pragma unroll
    for (int mi = 0; mi < 4; ++mi)
#pragma unroll
      for (int ni = 0; ni < 4; ++ni)
        acc[mi][ni] = __builtin_amdgcn_mfma_f32_16x16x32_bf16(a[mi], b[ni], acc[mi][ni], 0, 0, 0);
  }
}

// -------- grouped 128x128x(K=1024) bf16 MFMA GEMM, BK=64, queue-2 pipeline --------
// grid: flat 576, n0-major (bid&7 = n0 block) -> same B-rows pinned per XCD L2;
// consecutive bids share the A tile (L3 temporal locality).
// Per iter: barrier; issue loads for it+2; MFMA on buf[it&1]; ds_write it+1.
template <int MODE>
__global__ __launch_bounds__(256, 2) void gemm_k(
    const u16* __restrict__ A, const u16* __restrict__ Bt, const float* __restrict__ bias,
    const int* __restrict__ counts, const int* __restrict__ offsets,
    const int* __restrict__ tmap,
    u16* __restrict__ hid, float* __restrict__ Y, int h0, int accum) {
  const int bid = blockIdx.x;
  const int tile = bid >> 3, n0i = bid & 7;
  const int tv = tmap[tile];
  if (tv < 0) return;
  const int e = tv >> 16;
  const int m0 = (tv & 0xffff) * 128;
  const int cnt = counts[e];
  const int off_e = offsets[e];
  const int n0 = n0i * 128;

  __shared__ __align__(16) u16 As[2][8192];   // 2 x 16 KB
  __shared__ __align__(16) u16 Bs[2][8192];

  const int tid = threadIdx.x;
  const int wv = tid >> 6, ln = tid & 63;

  // staging ownership: (row r_ + 32p, chunk c_); XOR-swizzled LDS slot (measured 0 conflicts)
  const int r_ = tid >> 3, c_ = tid & 7;
  const int swz = (c_ ^ (r_ & 7)) * 8;
  const u16* gA = A + (size_t)(off_e + m0 + r_) * 1024 + c_ * 8;
  const u16* gB = Bt + ((size_t)e << 20) + (size_t)(n0 + r_) * 1024 + c_ * 8;
  const int lw = r_ * 64 + swz;

  const int wm = wv >> 1, wn = wv & 1;
  const int quad = ln >> 4, l15 = ln & 15;
  int aoff[2][4], boff[2][4];
#pragma unroll
  for (int ks = 0; ks < 2; ++ks) {
#pragma unroll
    for (int mi = 0; mi < 4; ++mi) {
      int ra = wm * 64 + mi * 16 + l15;
      aoff[ks][mi] = ra * 64 + (((ks * 4 + quad) ^ (ra & 7)) * 8);
      int rb = wn * 64 + mi * 16 + l15;
      boff[ks][mi] = rb * 64 + (((ks * 4 + quad) ^ (rb & 7)) * 8);
    }
  }

  f32x4 acc[4][4];
#pragma unroll
  for (int mi = 0; mi < 4; ++mi)
#pragma unroll
    for (int ni = 0; ni < 4; ++ni) acc[mi][ni] = (f32x4){0.f, 0.f, 0.f, 0.f};

  us8 q0[8], q1[8];
  ld8(gA, gB, 0, q0);
  wr8(&As[0][0], &Bs[0][0], lw, q0);        // waits vmcnt internally
  ld8(gA, gB, 1, q0);

  for (int it2 = 0; it2 < 8; ++it2) {       // 2 K-iters per body; q-index static
    __syncthreads();                        // buf0 ready
    if (it2 < 7) ld8(gA, gB, 2 * it2 + 2, q1);
    mfma_step(&As[0][0], &Bs[0][0], aoff, boff, acc);
    wr8(&As[1][0], &Bs[1][0], lw, q0);      // write L(2*it2+1)
    __syncthreads();                        // buf1 ready
    if (it2 < 7) ld8(gA, gB, 2 * it2 + 3, q0);
    mfma_step(&As[1][0], &Bs[1][0], aoff, boff, acc);
    if (it2 < 7) wr8(&As[0][0], &Bs[0][0], lw, q1);  // write L(2*it2+2)
  }

  // epilogue: D row = quad*4+r, col = l15 (m89/m91-verified layout)
#pragma unroll
  for (int mi = 0; mi < 4; ++mi) {
    const int mbase = m0 + wm * 64 + mi * 16 + quad * 4;
#pragma unroll
    for (int ni = 0; ni < 4; ++ni) {
      const int nloc = n0 + wn * 64 + ni * 16 + l15;
      float bv;
      if (MODE == 0) bv = bias[e * HDIM + h0 + nloc];
      else           bv = accum ? 0.f : bias[e * EDIM + nloc];
#pragma unroll
      for (int r = 0; r < 4; ++r) {
        const int m = mbase + r;
        if (m < cnt) {
          float v = acc[mi][ni][r] + bv;
          if (MODE == 0) {
            v = 0.5f * v * (1.f + erff(v * 0.70710678118654752f));  // exact gelu
            hid[(size_t)(off_e + m) * HC + nloc] = f2bf(v);
          } else {
            size_t yi = (size_t)(off_e + m) * EDIM + nloc;
            Y[yi] = accum ? (Y[yi] + v) : v;
          }
        }
      }
    }
  }
}

// ---------------- weighted combine over top-k rows (absolute sel_pos) ----------------
__global__ void combine_k(const float* __restrict__ Y, const int* __restrict__ sel_pos,
                          const float* __restrict__ sel_w, const int* __restrict__ topk_p,
                          float* __restrict__ out) {
  const int t = blockIdx.x;
  const int tid = threadIdx.x;              // 256 thr x 4 floats
  const int k = clampk(topk_p[0]);
  float a0 = 0.f, a1 = 0.f, a2 = 0.f, a3 = 0.f;
  for (int j = 0; j < k; ++j) {
    const float w = sel_w[t * 8 + j];
    const size_t row = (size_t)sel_pos[t * 8 + j];
    const float4 v = *(const float4*)(Y + row * EDIM + tid * 4);
    a0 += w * v.x; a1 += w * v.y; a2 += w * v.z; a3 += w * v.w;
  }
  float4 o; o.x = a0; o.y = a1; o.z = a2; o.w = a3;
  *(float4*)(out + (size_t)t * EDIM + tid * 4) = o;
}

extern "C" void kernel_launch(void* const* d_in, const int* in_sizes, int n_in,
                              void* d_out, int out_size, void* d_ws, size_t ws_size,
                              hipStream_t stream) {
  const float* x   = (const float*)d_in[0];
  const float* Wr  = (const float*)d_in[1];
  const float* br  = (const float*)d_in[2];
  const float* W1  = (const float*)d_in[3];
  const float* b1  = (const float*)d_in[4];
  const float* W2  = (const float*)d_in[5];
  const float* b2  = (const float*)d_in[6];
  const int* topk  = (const int*)d_in[7];
  float* out = (float*)d_out;

  char* ws = (char*)d_ws;
  size_t o = 0;
  auto alloc = [&](size_t bytes) -> char* {
    char* p = ws + o; o += (bytes + 255) & ~(size_t)255; return p;
  };
  int*   counts    = (int*)alloc(NEXP * 4);
  int*   offsets   = (int*)alloc(NEXP * 4);
  int*   tmap      = (int*)alloc(MAXTILES * 4);
  int*   sel_e     = (int*)alloc((size_t)TOKENS * 8 * 4);
  int*   sel_pos   = (int*)alloc((size_t)TOKENS * 8 * 4);
  int*   sel_lpos  = (int*)alloc((size_t)TOKENS * 8 * 4);
  float* sel_w     = (float*)alloc((size_t)TOKENS * 8 * 4);
  int*   row_token = (int*)alloc((size_t)TOKENS * 8 * 4);
  int*   hist_blk  = (int*)alloc((size_t)RBLK * NEXP * 4);
  int*   blk_base  = (int*)alloc((size_t)RBLK * NEXP * 4);
  u16*   xg        = (u16*)alloc((size_t)(MAXROWS + ROWPAD) * EDIM * 2);  //  17.0 MB
  u16*   W1t       = (u16*)alloc((size_t)NEXP * 1024 * 1024 * 2);         //  16.8 MB
  u16*   W2t       = (u16*)alloc((size_t)NEXP * 1024 * 1024 * 2);         //  16.8 MB
  u16*   hid       = (u16*)alloc((size_t)(MAXROWS + ROWPAD) * HC * 2);    //  17.0 MB
  float* Y         = (float*)alloc((size_t)MAXROWS * EDIM * 4);           //  33.5 MB
  // total ~= 102 MB of ws

  router_k<<<dim3(RBLK), dim3(256), 0, stream>>>(x, Wr, br, topk,
                                                 sel_e, sel_w, sel_lpos, hist_blk);
  scan_k<<<dim3(1), dim3(256), 0, stream>>>(hist_blk, counts, offsets, blk_base, tmap);
  finalize_k<<<dim3(TOKENS * 8 / 256), dim3(256), 0, stream>>>(sel_e, sel_lpos, blk_base,
                                                               topk, sel_pos, row_token);
  gather_cast_k<<<dim3(MAXROWS), dim3(256), 0, stream>>>(x, row_token, counts, xg);
  for (int c = 0; c < NCHUNK; ++c) {
    const int h0 = c * HC;
    transpose_k<<<dim3(16, 16, 16), dim3(256), 0, stream>>>(W1, W2, W1t, W2t, h0);
    gemm_k<0><<<dim3(MAXTILES * 8), dim3(256), 0, stream>>>(xg, W1t, b1, counts, offsets,
                                                            tmap, hid, nullptr, h0, 0);
    gemm_k<1><<<dim3(MAXTILES * 8), dim3(256), 0, stream>>>(hid, W2t, b2, counts, offsets,
                                                            tmap, nullptr, Y, h0,
                                                            c > 0 ? 1 : 0);
  }
  combine_k<<<dim3(TOKENS), dim3(256), 0, stream>>>(Y, sel_pos, sel_w, topk, out);
}

// Round 6
// 624.479 us; speedup vs baseline: 2.9064x; 1.3604x over previous
//
#include <hip/hip_runtime.h>
#include <hip/hip_bf16.h>
#include <cmath>
#include <cstdint>

// SparseMoE: B=2,S=2048 -> 4096 tokens, E=1024, N=8 experts, H=4096, top_k=2.
// fp32 I/O; internally bf16 MFMA grouped GEMM over the top-k expert rows only.
// R6: m97-replica GEMM core — 16KB single-buffer LDS, BK=32, coalesced
// global_load_lds (row-major [128][32] tiles, 16 rows/wave-instr), 4 blocks/CU
// via launch_bounds(256,4); bank conflicts on frag reads accepted (m97/m98:
// not the binding pipe). ws-adaptive: full-merge path (1 GEMM per layer, no Y
// accumulate round-trip) if ws >= ~254MB, else R5-style chunked loop.

typedef unsigned short u16;
typedef __attribute__((ext_vector_type(8))) short bf16x8;   // MFMA A/B frag (4 VGPR)
typedef __attribute__((ext_vector_type(4))) float f32x4;    // MFMA C/D frag
typedef __attribute__((ext_vector_type(8))) unsigned short us8;
typedef __attribute__((ext_vector_type(4))) unsigned short us4;

#define TOKENS  4096
#define EDIM    1024
#define NEXP    8
#define HDIM    4096
#define MAXROWS 8192      // top_k(=2) * TOKENS
#define ROWPAD  128       // tail staging may read past cnt; keep in-bounds
#define MAXTILES 72       // sum ceil(cnt_e/128) <= 64 + 7
#define RBLK    1024      // router blocks (4 tokens each)

__device__ __forceinline__ u16 f2bf(float f) {
  __hip_bfloat16 h = __float2bfloat16(f);   // RNE
  return *reinterpret_cast<u16*>(&h);
}
__device__ __forceinline__ int clampk(int k) {
  return k < 1 ? 1 : (k > 8 ? 8 : k);
}
// async global->LDS, 16B/lane; LDS dest = uniform base + lane*16 (HW rule)
__device__ __forceinline__ void async16(void* lds, const void* g) {
  __builtin_amdgcn_global_load_lds((const __attribute__((address_space(1))) void*)g,
                                   (__attribute__((address_space(3))) void*)lds,
                                   16, 0, 0);
}

// ---------- router: logits + top-k + softmax + block-local hist (no atomics) ----------
__global__ void router_k(const float* __restrict__ x, const float* __restrict__ Wr,
                         const float* __restrict__ br, const int* __restrict__ topk_p,
                         int* __restrict__ sel_e, float* __restrict__ sel_w,
                         int* __restrict__ sel_lpos, int* __restrict__ hist_blk) {
  __shared__ int wsel[4][8];
  const int blk = blockIdx.x;
  const int tid = threadIdx.x;
  const int wv = tid >> 6, ln = tid & 63;
  const int t = blk * 4 + wv;
  const int k = clampk(topk_p[0]);
  float acc[NEXP];
#pragma unroll
  for (int n = 0; n < NEXP; ++n) acc[n] = 0.f;
  const float* xr = x + (size_t)t * EDIM;
  for (int ei = ln; ei < EDIM; ei += 64) {
    float xv = xr[ei];
    float4 w0 = *(const float4*)(Wr + ei * NEXP);
    float4 w1 = *(const float4*)(Wr + ei * NEXP + 4);
    acc[0] += xv * w0.x; acc[1] += xv * w0.y; acc[2] += xv * w0.z; acc[3] += xv * w0.w;
    acc[4] += xv * w1.x; acc[5] += xv * w1.y; acc[6] += xv * w1.z; acc[7] += xv * w1.w;
  }
#pragma unroll
  for (int s = 32; s > 0; s >>= 1) {
#pragma unroll
    for (int n = 0; n < NEXP; ++n) acc[n] += __shfl_down(acc[n], s);
  }
  if (ln == 0) {
    float logit[NEXP];
#pragma unroll
    for (int n = 0; n < NEXP; ++n) logit[n] = acc[n] + br[n];
    bool used[NEXP];
#pragma unroll
    for (int n = 0; n < NEXP; ++n) used[n] = false;
    int se[NEXP]; float sw[NEXP];
    for (int j = 0; j < k; ++j) {           // strict > : lowest index wins ties (lax.top_k)
      int bi = 0; float bv = -INFINITY;
      for (int n = 0; n < NEXP; ++n)
        if (!used[n] && logit[n] > bv) { bv = logit[n]; bi = n; }
      used[bi] = true; se[j] = bi; sw[j] = bv;
    }
    float mx = sw[0], sum = 0.f;
    for (int j = 0; j < k; ++j) { sw[j] = expf(sw[j] - mx); sum += sw[j]; }
    float inv = 1.f / sum;
    for (int j = 0; j < k; ++j) {
      sel_e[t * 8 + j] = se[j];
      sel_w[t * 8 + j] = sw[j] * inv;
      wsel[wv][j] = se[j];
    }
  }
  __syncthreads();
  if (tid == 0) {
    int h[NEXP];
#pragma unroll
    for (int e = 0; e < NEXP; ++e) h[e] = 0;
    for (int w = 0; w < 4; ++w)
      for (int j = 0; j < k; ++j) {
        int e = wsel[w][j];
        sel_lpos[(blk * 4 + w) * 8 + j] = h[e]++;
      }
#pragma unroll
    for (int e = 0; e < NEXP; ++e) hist_blk[blk * NEXP + e] = h[e];
  }
}

// ---------- scan: per-expert exclusive scan over 1024 block hists ----------
__global__ void scan_k(const int* __restrict__ hist_blk, int* __restrict__ counts,
                       int* __restrict__ offsets, int* __restrict__ blk_base,
                       int* __restrict__ tmap) {
  __shared__ int sc[NEXP][257];
  __shared__ int offs[NEXP];
  const int tid = threadIdx.x;              // 256 threads, 4 hist rows each
  int h[4][NEXP], part[NEXP];
#pragma unroll
  for (int e = 0; e < NEXP; ++e) part[e] = 0;
#pragma unroll
  for (int r = 0; r < 4; ++r) {
    const int row = tid * 4 + r;
#pragma unroll
    for (int e = 0; e < NEXP; ++e) { h[r][e] = hist_blk[row * NEXP + e]; part[e] += h[r][e]; }
  }
#pragma unroll
  for (int e = 0; e < NEXP; ++e) sc[e][tid] = part[e];
  __syncthreads();
  for (int d = 1; d < 256; d <<= 1) {       // Hillis-Steele inclusive scan x8
    int v[NEXP];
#pragma unroll
    for (int e = 0; e < NEXP; ++e) v[e] = (tid >= d) ? sc[e][tid - d] : 0;
    __syncthreads();
#pragma unroll
    for (int e = 0; e < NEXP; ++e) sc[e][tid] += v[e];
    __syncthreads();
  }
  if (tid == 0) {
    int s = 0;
    for (int e = 0; e < NEXP; ++e) {
      int tot = sc[e][255];
      offsets[e] = s; offs[e] = s; counts[e] = tot; s += tot;
    }
    int nt = 0;
    for (int e = 0; e < NEXP; ++e) {
      int nb = (counts[e] + 127) >> 7;
      for (int b = 0; b < nb && nt < MAXTILES; ++b) tmap[nt++] = (e << 16) | b;
    }
    for (; nt < MAXTILES; ++nt) tmap[nt] = -1;
  }
  __syncthreads();
#pragma unroll
  for (int e = 0; e < NEXP; ++e) {
    int run = offs[e] + sc[e][tid] - part[e];   // absolute exclusive base
#pragma unroll
    for (int r = 0; r < 4; ++r) {
      blk_base[(tid * 4 + r) * NEXP + e] = run;
      run += h[r][e];
    }
  }
}

// ---------- finalize: absolute positions + row->token scatter ----------
__global__ void finalize_k(const int* __restrict__ sel_e, const int* __restrict__ sel_lpos,
                           const int* __restrict__ blk_base, const int* __restrict__ topk_p,
                           int* __restrict__ sel_pos, int* __restrict__ row_token) {
  const int k = clampk(topk_p[0]);
  const int i = blockIdx.x * 256 + threadIdx.x;
  if (i >= TOKENS * k) return;
  const int t = i / k, j = i - t * k;
  const int e = sel_e[t * 8 + j];
  const int pos = blk_base[(t >> 2) * NEXP + e] + sel_lpos[t * 8 + j];
  sel_pos[t * 8 + j] = pos;                 // absolute compact-row index
  row_token[pos] = t;
}

// ---------------- gather+cast: xg[row] = bf16(x[row_token[row]]) ----------------
__global__ void gather_cast_k(const float* __restrict__ x, const int* __restrict__ row_token,
                              const int* __restrict__ counts, u16* __restrict__ xg) {
  __shared__ int tot_s;
  if (threadIdx.x == 0) {
    int t = 0;
#pragma unroll
    for (int e = 0; e < NEXP; ++e) t += counts[e];
    tot_s = t;
  }
  __syncthreads();
  const int row = blockIdx.x;
  if (row >= tot_s) return;                 // pad rows stay poisoned (finite bf16)
  const float* src = x + (size_t)row_token[row] * EDIM;
  u16* dst = xg + (size_t)row * EDIM;
  const int i = threadIdx.x;                // 256 thr x float4
  float4 v = *(const float4*)(src + i * 4);
  us4 o; o[0] = f2bf(v.x); o[1] = f2bf(v.y); o[2] = f2bf(v.z); o[3] = f2bf(v.w);
  *(us4*)(dst + i * 4) = o;
}

// ------ transpose+downcast 1024-wide H-chunks of W1 and W2 ------
// full=1: z in [0,64): z<32 -> W1 (e=z>>2, h0=(z&3)*1024), else W2; full strides.
// full=0: z in [0,16): z<8 -> W1 chunk h0c, else W2 chunk h0c; chunk strides.
__global__ void transpose_k(const float* __restrict__ W1, const float* __restrict__ W2,
                            u16* __restrict__ W1t, u16* __restrict__ W2t,
                            int full, int h0c) {
  __shared__ __align__(16) u16 T[64][68];   // +4 pad
  const int z = blockIdx.z;
  int mat, e, h0;
  if (full) { mat = z < 32 ? 0 : 1; int zz = mat ? z - 32 : z; e = zz >> 2; h0 = (zz & 3) * 1024; }
  else      { mat = z < 8 ? 0 : 1;  e = mat ? z - 8 : z;      h0 = h0c; }
  const size_t oes = full ? (size_t)HDIM * EDIM : (size_t)1024 * 1024;
  const float* in; size_t istride;
  if (mat == 0) { in = W1 + (size_t)e * EDIM * HDIM + h0;            istride = HDIM; }
  else          { in = W2 + (size_t)e * HDIM * EDIM + (size_t)h0 * EDIM; istride = EDIM; }
  const int r0 = blockIdx.y * 64, c0 = blockIdx.x * 64;
  const int tid = threadIdx.x;
#pragma unroll
  for (int it = 0; it < 4; ++it) {
    int cell = it * 256 + tid;              // 1024 cells: rl(64) x c4(16)
    int rl = cell >> 4, c4 = (cell & 15) * 4;
    float4 v = *(const float4*)(in + (size_t)(r0 + rl) * istride + c0 + c4);
    us4 o; o[0] = f2bf(v.x); o[1] = f2bf(v.y); o[2] = f2bf(v.z); o[3] = f2bf(v.w);
    *(us4*)&T[rl][c4] = o;
  }
  __syncthreads();
#pragma unroll
  for (int it = 0; it < 2; ++it) {
    int cell = it * 256 + tid;              // 512 cells: cl(64) x r8(8)
    int cl = cell >> 3, r8 = (cell & 7) * 8;
    us8 o;
#pragma unroll
    for (int j = 0; j < 8; ++j) o[j] = T[r8 + j][cl];
    u16* out;
    if (mat == 0) {  // W1t[e][h][ei]
      int orow = (full ? h0 : 0) + c0 + cl;
      out = W1t + (size_t)e * oes + (size_t)orow * 1024 + r0 + r8;
    } else {         // W2t[e][ep][h]
      int ost = full ? HDIM : 1024;
      out = W2t + (size_t)e * oes + (size_t)(c0 + cl) * ost + (full ? h0 : 0) + r0 + r8;
    }
    *(us8*)out = o;
  }
}

// -------- grouped 128x128 bf16 MFMA GEMM, BK=32, m97 structure --------
// LDS: As/Bs 8KB each, row-major [128 rows][32 k] (64B rows), single-buffered.
// Staging: global_load_lds x4/thread, wave-instr = 16 rows x 64B (coalesced).
// Frag reads: ds_read_b128 at row*64 + quad*16 (8-way bank conflict accepted).
// Grid 1D, n0-fastest: XCD = bid%8 pins B slices per-XCD L2; A broadcast via L3.
template <int MODE>
__global__ __launch_bounds__(256, 4) void gemm_k(
    const u16* __restrict__ A, int astride,
    const u16* __restrict__ Bt, size_t b_estride, int bstride, int kblocks,
    const float* __restrict__ bias, int bias_dim, int bias_col0,
    const int* __restrict__ counts, const int* __restrict__ offsets,
    const int* __restrict__ tmap,
    u16* __restrict__ hid, int hid_stride, float* __restrict__ Y, int accum, int NB) {
  const int bid = blockIdx.x;
  const int n0i = bid % NB, tile = bid / NB;
  const int tv = tmap[tile];
  if (tv < 0) return;
  const int e = tv >> 16;
  const int m0 = (tv & 0xffff) << 7;
  const int cnt = counts[e], off_e = offsets[e];
  const int n0 = n0i << 7;

  __shared__ __align__(16) u16 As[4096];    // 8 KB: 128 rows x 32 k
  __shared__ __align__(16) u16 Bs[4096];

  const int tid = threadIdx.x;
  const int wv = tid >> 6, ln = tid & 63;

  // staging: pass p covers rows p*64..p*64+63; wave wv covers 16 rows (1KB);
  // lane ln -> row wv*16 + (ln>>2), 16B chunk (ln&3). Lane-linear LDS = row-major.
  const int srow = wv * 16 + (ln >> 2);
  const int scol = (ln & 3) * 8;            // u16 units
  const u16* gA0 = A + (size_t)(off_e + m0 + srow) * astride + scol;
  const u16* gA1 = gA0 + (size_t)64 * astride;
  const u16* gB0 = Bt + (size_t)e * b_estride + (size_t)(n0 + srow) * bstride + scol;
  const u16* gB1 = gB0 + (size_t)64 * bstride;
  u16* lA0 = As + wv * 512;  u16* lA1 = As + 2048 + wv * 512;
  u16* lB0 = Bs + wv * 512;  u16* lB1 = Bs + 2048 + wv * 512;

  const int wm = wv >> 1, wn = wv & 1;
  const int quad = ln >> 4, l15 = ln & 15;
  int aoff[4], boff[4];
#pragma unroll
  for (int mi = 0; mi < 4; ++mi) {
    aoff[mi] = (wm * 64 + mi * 16 + l15) * 32 + quad * 8;
    boff[mi] = (wn * 64 + mi * 16 + l15) * 32 + quad * 8;
  }

  f32x4 acc[4][4];
#pragma unroll
  for (int mi = 0; mi < 4; ++mi)
#pragma unroll
    for (int ni = 0; ni < 4; ++ni) acc[mi][ni] = (f32x4){0.f, 0.f, 0.f, 0.f};

  for (int kb = 0; kb < kblocks; ++kb) {
    const int k0 = kb * 32;
    __syncthreads();                        // prev iter's LDS reads done
    async16(lA0, gA0 + k0);
    async16(lA1, gA1 + k0);
    async16(lB0, gB0 + k0);
    async16(lB1, gB1 + k0);
    __syncthreads();                        // drains vmcnt -> LDS ready
    bf16x8 a[4], b[4];
#pragma unroll
    for (int mi = 0; mi < 4; ++mi) a[mi] = *(const bf16x8*)(As + aoff[mi]);
#pragma unroll
    for (int ni = 0; ni < 4; ++ni) b[ni] = *(const bf16x8*)(Bs + boff[ni]);
#pragma unroll
    for (int mi = 0; mi < 4; ++mi)
#pragma unroll
      for (int ni = 0; ni < 4; ++ni)
        acc[mi][ni] = __builtin_amdgcn_mfma_f32_16x16x32_bf16(a[mi], b[ni], acc[mi][ni], 0, 0, 0);
  }

  // epilogue: D row = quad*4+r, col = l15 (m89/m91-verified layout)
#pragma unroll
  for (int mi = 0; mi < 4; ++mi) {
    const int mbase = m0 + wm * 64 + mi * 16 + quad * 4;
#pragma unroll
    for (int ni = 0; ni < 4; ++ni) {
      const int nloc = n0 + wn * 64 + ni * 16 + l15;
      const float bv0 = bias[e * bias_dim + bias_col0 + nloc];
      const float bv = (MODE == 1 && accum) ? 0.f : bv0;
#pragma unroll
      for (int r = 0; r < 4; ++r) {
        const int m = mbase + r;
        if (m < cnt) {
          float v = acc[mi][ni][r] + bv;
          if (MODE == 0) {
            v = 0.5f * v * (1.f + erff(v * 0.70710678118654752f));  // exact gelu
            hid[(size_t)(off_e + m) * hid_stride + nloc] = f2bf(v);
          } else {
            size_t yi = (size_t)(off_e + m) * EDIM + nloc;
            Y[yi] = accum ? (Y[yi] + v) : v;
          }
        }
      }
    }
  }
}

// ---------------- weighted combine over top-k rows (absolute sel_pos) ----------------
__global__ void combine_k(const float* __restrict__ Y, const int* __restrict__ sel_pos,
                          const float* __restrict__ sel_w, const int* __restrict__ topk_p,
                          float* __restrict__ out) {
  const int t = blockIdx.x;
  const int tid = threadIdx.x;              // 256 thr x 4 floats
  const int k = clampk(topk_p[0]);
  float a0 = 0.f, a1 = 0.f, a2 = 0.f, a3 = 0.f;
  for (int j = 0; j < k; ++j) {
    const float w = sel_w[t * 8 + j];
    const size_t row = (size_t)sel_pos[t * 8 + j];
    const float4 v = *(const float4*)(Y + row * EDIM + tid * 4);
    a0 += w * v.x; a1 += w * v.y; a2 += w * v.z; a3 += w * v.w;
  }
  float4 o; o.x = a0; o.y = a1; o.z = a2; o.w = a3;
  *(float4*)(out + (size_t)t * EDIM + tid * 4) = o;
}

extern "C" void kernel_launch(void* const* d_in, const int* in_sizes, int n_in,
                              void* d_out, int out_size, void* d_ws, size_t ws_size,
                              hipStream_t stream) {
  const float* x   = (const float*)d_in[0];
  const float* Wr  = (const float*)d_in[1];
  const float* br  = (const float*)d_in[2];
  const float* W1  = (const float*)d_in[3];
  const float* b1  = (const float*)d_in[4];
  const float* W2  = (const float*)d_in[5];
  const float* b2  = (const float*)d_in[6];
  const int* topk  = (const int*)d_in[7];
  float* out = (float*)d_out;

  char* ws = (char*)d_ws;
  size_t o = 0;
  auto alloc = [&](size_t bytes) -> char* {
    char* p = ws + o; o += (bytes + 255) & ~(size_t)255; return p;
  };
  int*   counts    = (int*)alloc(NEXP * 4);
  int*   offsets   = (int*)alloc(NEXP * 4);
  int*   tmap      = (int*)alloc(MAXTILES * 4);
  int*   sel_e     = (int*)alloc((size_t)TOKENS * 8 * 4);
  int*   sel_pos   = (int*)alloc((size_t)TOKENS * 8 * 4);
  int*   sel_lpos  = (int*)alloc((size_t)TOKENS * 8 * 4);
  float* sel_w     = (float*)alloc((size_t)TOKENS * 8 * 4);
  int*   row_token = (int*)alloc((size_t)TOKENS * 8 * 4);
  int*   hist_blk  = (int*)alloc((size_t)RBLK * NEXP * 4);
  int*   blk_base  = (int*)alloc((size_t)RBLK * NEXP * 4);
  u16*   xg        = (u16*)alloc((size_t)(MAXROWS + ROWPAD) * EDIM * 2);  // 17.0 MB
  float* Y         = (float*)alloc((size_t)MAXROWS * EDIM * 4);           // 33.6 MB

  // decide path from remaining ws
  const size_t full_need  = ((size_t)NEXP * HDIM * EDIM * 2) * 2            // W1t+W2t 134.2 MB
                          + (size_t)(MAXROWS + ROWPAD) * HDIM * 2 + 4096;   // hid 68.2 MB
  const size_t chunk_need = ((size_t)NEXP * 1024 * 1024 * 2) * 2
                          + (size_t)(MAXROWS + ROWPAD) * 1024 * 2 + 4096;
  const bool full = (ws_size - o) >= full_need;
  u16 *W1t, *W2t, *hid;
  if (full) {
    W1t = (u16*)alloc((size_t)NEXP * HDIM * EDIM * 2);
    W2t = (u16*)alloc((size_t)NEXP * HDIM * EDIM * 2);
    hid = (u16*)alloc((size_t)(MAXROWS + ROWPAD) * HDIM * 2);
  } else {
    W1t = (u16*)alloc((size_t)NEXP * 1024 * 1024 * 2);
    W2t = (u16*)alloc((size_t)NEXP * 1024 * 1024 * 2);
    hid = (u16*)alloc((size_t)(MAXROWS + ROWPAD) * 1024 * 2);
    (void)chunk_need;
  }

  router_k<<<dim3(RBLK), dim3(256), 0, stream>>>(x, Wr, br, topk,
                                                 sel_e, sel_w, sel_lpos, hist_blk);
  scan_k<<<dim3(1), dim3(256), 0, stream>>>(hist_blk, counts, offsets, blk_base, tmap);
  finalize_k<<<dim3(TOKENS * 8 / 256), dim3(256), 0, stream>>>(sel_e, sel_lpos, blk_base,
                                                               topk, sel_pos, row_token);
  gather_cast_k<<<dim3(MAXROWS), dim3(256), 0, stream>>>(x, row_token, counts, xg);

  if (full) {
    transpose_k<<<dim3(16, 16, 64), dim3(256), 0, stream>>>(W1, W2, W1t, W2t, 1, 0);
    // layer 1: N=4096 merged, K=1024
    gemm_k<0><<<dim3(MAXTILES * 32), dim3(256), 0, stream>>>(
        xg, EDIM, W1t, (size_t)HDIM * EDIM, 1024, 32,
        b1, HDIM, 0, counts, offsets, tmap, hid, HDIM, nullptr, 0, 32);
    // layer 2: K=4096 merged, single pass (no Y round-trip)
    gemm_k<1><<<dim3(MAXTILES * 8), dim3(256), 0, stream>>>(
        hid, HDIM, W2t, (size_t)HDIM * EDIM, HDIM, 128,
        b2, EDIM, 0, counts, offsets, tmap, nullptr, 0, Y, 0, 8);
  } else {
    for (int c = 0; c < 4; ++c) {
      const int h0 = c * 1024;
      transpose_k<<<dim3(16, 16, 16), dim3(256), 0, stream>>>(W1, W2, W1t, W2t, 0, h0);
      gemm_k<0><<<dim3(MAXTILES * 8), dim3(256), 0, stream>>>(
          xg, EDIM, W1t, (size_t)1024 * 1024, 1024, 32,
          b1, HDIM, h0, counts, offsets, tmap, hid, 1024, nullptr, 0, 8);
      gemm_k<1><<<dim3(MAXTILES * 8), dim3(256), 0, stream>>>(
          hid, 1024, W2t, (size_t)1024 * 1024, 1024, 32,
          b2, EDIM, 0, counts, offsets, tmap, nullptr, 0, Y, c > 0 ? 1 : 0, 8);
    }
  }
  combine_k<<<dim3(TOKENS), dim3(256), 0, stream>>>(Y, sel_pos, sel_w, topk, out);
}